// Round 4
// baseline (1133.456 us; speedup 1.0000x reference)
//
#include <hip/hip_runtime.h>
#include <hip/hip_bf16.h>

#define NNODES 50000
#define NEDGES 800000
#define DF 128
#define EPS 0.001f

typedef __bf16 bf16x8 __attribute__((ext_vector_type(8)));
typedef float  f32x4  __attribute__((ext_vector_type(4)));

// ---- weight cast, native layouts: wt1[o][i]=bw; wt2[o][i*8+b]=sw (both row-major) ----
__global__ void cast_weights(const float* __restrict__ bwl, const float* __restrict__ swl,
                             const float* __restrict__ bwc, const float* __restrict__ swc,
                             __bf16* wt1l, __bf16* wt2l, __bf16* wt1c, __bf16* wt2c) {
    int gid = blockIdx.x * 256 + threadIdx.x;          // 294912 threads total
    if (gid < 16384)        wt1l[gid]          = (__bf16)bwl[gid];
    else if (gid < 147456)  wt2l[gid - 16384]  = (__bf16)swl[gid - 16384];
    else if (gid < 163840)  wt1c[gid - 147456] = (__bf16)bwc[gid - 147456];
    else                    wt2c[gid - 163840] = (__bf16)swc[gid - 163840];
}

// ---------------- CSR build ----------------
__global__ void deg_count(const int* __restrict__ ei, int* __restrict__ deg) {
    int e = blockIdx.x * 256 + threadIdx.x;
    if (e >= NEDGES) return;
    atomicAdd(&deg[ei[NEDGES + e]], 1);
}

#define SCHUNK 49
__global__ __launch_bounds__(1024) void scan_rowptr(const int* __restrict__ deg,
                                                    int* __restrict__ rowptr) {
    __shared__ int sums[1024];
    const int t = threadIdx.x;
    const int base = t * SCHUNK;
    int loc[SCHUNK];
    int s = 0;
#pragma unroll
    for (int j = 0; j < SCHUNK; ++j) {
        int i = base + j;
        int v = (i < NNODES) ? deg[i] : 0;
        loc[j] = s;
        s += v;
    }
    sums[t] = s;
    __syncthreads();
    for (int off = 1; off < 1024; off <<= 1) {
        int v = (t >= off) ? sums[t - off] : 0;
        __syncthreads();
        sums[t] += v;
        __syncthreads();
    }
    int excl = sums[t] - s;
#pragma unroll
    for (int j = 0; j < SCHUNK; ++j) {
        int i = base + j;
        if (i < NNODES) rowptr[i] = excl + loc[j];
    }
    if (t == 1023) rowptr[NNODES] = sums[1023];
}

__global__ void fill_csr(const int* __restrict__ ei, const int* __restrict__ deg,
                         const int* __restrict__ rowptr, int* __restrict__ cnt,
                         int* __restrict__ esrc, float* __restrict__ ew) {
    int e = blockIdx.x * 256 + threadIdx.x;
    if (e >= NEDGES) return;
    int s = ei[e];
    int d = ei[NEDGES + e];
    float w = rsqrtf((float)(deg[s] + 1)) * rsqrtf((float)(deg[d] + 1));
    int p = rowptr[d] + atomicAdd(&cnt[d], 1);
    esrc[p] = s;
    ew[p] = w;
}

// ---------------- aggregation: one 32-lane half-wave per node, no atomics ----
__global__ __launch_bounds__(256) void agg_gather(
        const int* __restrict__ rowptr, const int* __restrict__ esrc,
        const float* __restrict__ ew, const float* __restrict__ h,
        float* __restrict__ agg) {
    const int tid = blockIdx.x * 256 + threadIdx.x;
    const int n = tid >> 5;
    const int l = tid & 31;
    if (n >= NNODES) return;
    int p  = rowptr[n];
    const int pe = rowptr[n + 1];
    f32x4 acc = {0.0f, 0.0f, 0.0f, 0.0f};
    for (; p + 1 < pe; p += 2) {
        int   s0 = esrc[p],  s1 = esrc[p + 1];
        float w0 = ew[p],    w1 = ew[p + 1];
        f32x4 v0 = *(const f32x4*)(h + (size_t)s0 * DF + l * 4);
        f32x4 v1 = *(const f32x4*)(h + (size_t)s1 * DF + l * 4);
        acc[0] += w0 * v0[0]; acc[1] += w0 * v0[1];
        acc[2] += w0 * v0[2]; acc[3] += w0 * v0[3];
        acc[0] += w1 * v1[0]; acc[1] += w1 * v1[1];
        acc[2] += w1 * v1[2]; acc[3] += w1 * v1[3];
    }
    if (p < pe) {
        int   s0 = esrc[p];
        float w0 = ew[p];
        f32x4 v0 = *(const f32x4*)(h + (size_t)s0 * DF + l * 4);
        acc[0] += w0 * v0[0]; acc[1] += w0 * v0[1];
        acc[2] += w0 * v0[2]; acc[3] += w0 * v0[3];
    }
    *(f32x4*)(agg + (size_t)n * DF + l * 4) = acc;
}

// ---- fused dual-KAN GEMM, in-register A expansion, Euler epilogue --------------
// K-chunks t=0..71:  [0,4): silu(h)*wt1l   [4,36): spline(h)*wt2l
//                    [36,40): silu(agg)*wt1c [40,72): spline(agg)*wt2c
// k-order within spline segment: k = i*8 + b  (matches sw native layout)
// Block: 64 rows x 128 cols; 4 col-split waves (wave w -> cols w*32..w*32+31).
__global__ __launch_bounds__(256) void kan_fused(
        const float* __restrict__ h, const float* __restrict__ agg,
        const __bf16* __restrict__ wt1l, const __bf16* __restrict__ wt2l,
        const __bf16* __restrict__ wt1c, const __bf16* __restrict__ wt2c,
        float* __restrict__ out) {
    __shared__ __bf16 Bs[2][128 * 40];       // [buf][o][kk], stride 40 (80B, 2-way ok)

    const int tid  = threadIdx.x;
    const int lane = tid & 63;
    const int w    = tid >> 6;               // wave = col-split
    const int q    = lane >> 4;
    const int l15  = lane & 15;
    const int n0   = blockIdx.x * 64;

    const int so = tid & 127;                // staging: o
    const int sh = tid >> 7;                 // staging: kk half

    f32x4 acc[4][2] = {};

    auto src_of = [&](int t, const __bf16*& bsrc, const float*& asrc,
                      int& kc, int& brow, bool& spl) {
        if (t < 4)       { bsrc = wt1l; asrc = h;   kc = t;      brow = 128;  spl = false; }
        else if (t < 36) { bsrc = wt2l; asrc = h;   kc = t - 4;  brow = 1024; spl = true;  }
        else if (t < 40) { bsrc = wt1c; asrc = agg; kc = t - 36; brow = 128;  spl = false; }
        else             { bsrc = wt2c; asrc = agg; kc = t - 40; brow = 1024; spl = true;  }
    };

    auto stage = [&](int t, int buf) {
        const __bf16* bsrc; const float* asrc; int kc, brow; bool spl;
        src_of(t, bsrc, asrc, kc, brow, spl);
        const uint4* g = (const uint4*)(bsrc + (size_t)so * brow + kc * 32 + sh * 16);
        uint4 g0 = g[0], g1 = g[1];
        *(uint4*)&Bs[buf][so * 40 + sh * 16]     = g0;
        *(uint4*)&Bs[buf][so * 40 + sh * 16 + 8] = g1;
    };

    // expand A fragment for row-frag mi of chunk t: lane holds A[row][q*8 + j]
    auto expand = [&](int t, int mi) -> bf16x8 {
        const __bf16* bsrc; const float* asrc; int kc, brow; bool spl;
        src_of(t, bsrc, asrc, kc, brow, spl);
        const int row = n0 + mi * 16 + l15;
        const bool rok = row < NNODES;
        bf16x8 a;
        if (spl) {
            // one element (row, i=kc*4+q): j = basis index b
            const int i = kc * 4 + q;
            float x = rok ? asrc[(size_t)row * DF + i] : 0.0f;
            float f  = (x + 2.2f) * 2.5f;     // (x - t0)/hstep
            float fi = floorf(f);
            int   idx = (int)fi;
            float u  = f - fi;
            float u2 = u * u, u3 = u2 * u;
            float om = 1.0f - u;
            float Wa = u3 * (1.0f / 6.0f);
            float Wb = (((-3.0f * u + 3.0f) * u + 3.0f) * u + 1.0f) * (1.0f / 6.0f);
            float Wc = ((3.0f * u - 6.0f) * u2 + 4.0f) * (1.0f / 6.0f);
            float Wd = om * om * om * (1.0f / 6.0f);
#pragma unroll
            for (int b = 0; b < 8; ++b) {
                float v = (idx == b)     ? Wa
                        : (idx == b + 1) ? Wb
                        : (idx == b + 2) ? Wc
                        : (idx == b + 3) ? Wd : 0.0f;
                a[b] = (__bf16)v;
            }
        } else {
            // 8 silu values: i = kc*32 + q*8 + j
            const int i0 = kc * 32 + q * 8;
            f32x4 xa = {0, 0, 0, 0}, xb = {0, 0, 0, 0};
            if (rok) {
                xa = *(const f32x4*)(asrc + (size_t)row * DF + i0);
                xb = *(const f32x4*)(asrc + (size_t)row * DF + i0 + 4);
            }
#pragma unroll
            for (int j = 0; j < 4; ++j) { float x = xa[j]; a[j]     = (__bf16)(x / (1.0f + __expf(-x))); }
#pragma unroll
            for (int j = 0; j < 4; ++j) { float x = xb[j]; a[4 + j] = (__bf16)(x / (1.0f + __expf(-x))); }
        }
        return a;
    };

    stage(0, 0);
    __syncthreads();

#pragma unroll 2
    for (int t = 0; t < 72; ++t) {
        const int buf = t & 1;
        if (t + 1 < 72) stage(t + 1, buf ^ 1);
        bf16x8 aF[4];
#pragma unroll
        for (int mi = 0; mi < 4; ++mi) aF[mi] = expand(t, mi);
        bf16x8 bF[2];
#pragma unroll
        for (int nj = 0; nj < 2; ++nj)
            bF[nj] = *(const bf16x8*)&Bs[buf][(w * 32 + nj * 16 + l15) * 40 + q * 8];
#pragma unroll
        for (int mi = 0; mi < 4; ++mi)
#pragma unroll
            for (int nj = 0; nj < 2; ++nj)
                acc[mi][nj] = __builtin_amdgcn_mfma_f32_16x16x32_bf16(
                    aF[mi], bF[nj], acc[mi][nj], 0, 0, 0);
        __syncthreads();
    }

    // epilogue: Euler update; D layout row = q*4+r, col = l15 (m89-verified)
#pragma unroll
    for (int mi = 0; mi < 4; ++mi) {
#pragma unroll
        for (int nj = 0; nj < 2; ++nj) {
#pragma unroll
            for (int r = 0; r < 4; ++r) {
                int rr  = n0 + mi * 16 + q * 4 + r;
                int col = w * 32 + nj * 16 + l15;
                if (rr < NNODES) {
                    size_t idx = (size_t)rr * DF + col;
                    out[idx] = h[idx] + EPS * acc[mi][nj][r];
                }
            }
        }
    }
}

extern "C" void kernel_launch(void* const* d_in, const int* in_sizes, int n_in,
                              void* d_out, int out_size, void* d_ws, size_t ws_size,
                              hipStream_t stream) {
    const float* x   = (const float*)d_in[0];
    const int*   ei  = (const int*)d_in[1];     // edge_index [2,E] int32
    const float* bwl = (const float*)d_in[2];
    const float* swl = (const float*)d_in[3];
    const float* bwc = (const float*)d_in[4];
    const float* swc = (const float*)d_in[5];
    float* out = (float*)d_out;

    char* ws = (char*)d_ws;
    int*    deg    = (int*)  (ws + 0);            //   200,000
    int*    cnt    = (int*)  (ws + 200064);       //   200,000
    int*    rowptr = (int*)  (ws + 400128);       //   200,004
    int*    esrc   = (int*)  (ws + 600192);       // 3,200,000
    float*  ew     = (float*)(ws + 3800192);      // 3,200,000
    float*  agg    = (float*)(ws + 7000192);      // 25,600,000
    __bf16* wt1l   = (__bf16*)(ws + 32600192);    //    32,768
    __bf16* wt2l   = (__bf16*)(ws + 32632960);    //   262,144
    __bf16* wt1c   = (__bf16*)(ws + 32895104);    //    32,768
    __bf16* wt2c   = (__bf16*)(ws + 32927872);    //   262,144  (total ~33.2 MB)

    cast_weights<<<1152, 256, 0, stream>>>(bwl, swl, bwc, swc, wt1l, wt2l, wt1c, wt2c);

    hipMemsetAsync(deg, 0, NNODES * sizeof(int), stream);
    hipMemsetAsync(cnt, 0, NNODES * sizeof(int), stream);
    deg_count<<<(NEDGES + 255) / 256, 256, 0, stream>>>(ei, deg);
    scan_rowptr<<<1, 1024, 0, stream>>>(deg, rowptr);
    fill_csr<<<(NEDGES + 255) / 256, 256, 0, stream>>>(ei, deg, rowptr, cnt, esrc, ew);

    const int gemm_grid = (NNODES + 63) / 64;     // 782
    const float* h = x;
    for (int step = 0; step < 2; ++step) {        // delta_t = 2
        agg_gather<<<(NNODES * 32 + 255) / 256, 256, 0, stream>>>(rowptr, esrc, ew, h, agg);
        kan_fused<<<gemm_grid, 256, 0, stream>>>(h, agg, wt1l, wt2l, wt1c, wt2c, out);
        h = out;
    }
}

// Round 5
// 637.062 us; speedup vs baseline: 1.7792x; 1.7792x over previous
//
#include <hip/hip_runtime.h>
#include <hip/hip_bf16.h>

#define NNODES 50000
#define NEDGES 800000
#define DF 128
#define KEXP 1280              // 10 planes * 128 (plane 9 = zero pad)
#define EPS 0.001f

typedef __bf16 bf16x8 __attribute__((ext_vector_type(8)));
typedef __bf16 bf16x4 __attribute__((ext_vector_type(4)));
typedef float  f32x4  __attribute__((ext_vector_type(4)));

// ---- weight pre-transform: wt[o][k], k = c*128 + i; c=0 base, 1..8 spline, 9 zero ----
__global__ void build_wt(const float* __restrict__ bwl, const float* __restrict__ swl,
                         const float* __restrict__ bwc, const float* __restrict__ swc,
                         __bf16* __restrict__ wtl, __bf16* __restrict__ wtc) {
    int gid = blockIdx.x * 256 + threadIdx.x;      // DF*KEXP threads in x
    const float* bw = blockIdx.y ? bwc : bwl;
    const float* sw = blockIdx.y ? swc : swl;
    __bf16*      wt = blockIdx.y ? wtc : wtl;
    int o = gid / KEXP;
    int k = gid - o * KEXP;
    int c = k >> 7, i = k & 127;
    float v = 0.0f;
    if (c == 0)      v = bw[o * DF + i];
    else if (c <= 8) v = sw[(o * DF + i) * 8 + (c - 1)];
    wt[gid] = (__bf16)v;
}

// ---- bf16 shadow of x (gather traffic halver) ----
__global__ void cast_x(const float* __restrict__ x, __bf16* __restrict__ xb) {
    int i = blockIdx.x * 256 + threadIdx.x;        // 800,000 threads, 8 elems each
    f32x4 a = ((const f32x4*)x)[2 * i];
    f32x4 b = ((const f32x4*)x)[2 * i + 1];
    bf16x8 o;
    o[0] = (__bf16)a[0]; o[1] = (__bf16)a[1]; o[2] = (__bf16)a[2]; o[3] = (__bf16)a[3];
    o[4] = (__bf16)b[0]; o[5] = (__bf16)b[1]; o[6] = (__bf16)b[2]; o[7] = (__bf16)b[3];
    ((bf16x8*)xb)[i] = o;
}

// ---------------- CSR build ----------------
__global__ void deg_count(const int* __restrict__ ei, int* __restrict__ deg) {
    int e = blockIdx.x * 256 + threadIdx.x;
    if (e >= NEDGES) return;
    atomicAdd(&deg[ei[NEDGES + e]], 1);
}

#define SCHUNK 49
__global__ __launch_bounds__(1024) void scan_rowptr(const int* __restrict__ deg,
                                                    int* __restrict__ rowptr) {
    __shared__ int sums[1024];
    const int t = threadIdx.x;
    const int base = t * SCHUNK;
    int loc[SCHUNK];
    int s = 0;
#pragma unroll
    for (int j = 0; j < SCHUNK; ++j) {
        int i = base + j;
        int v = (i < NNODES) ? deg[i] : 0;
        loc[j] = s;
        s += v;
    }
    sums[t] = s;
    __syncthreads();
    for (int off = 1; off < 1024; off <<= 1) {
        int v = (t >= off) ? sums[t - off] : 0;
        __syncthreads();
        sums[t] += v;
        __syncthreads();
    }
    int excl = sums[t] - s;
#pragma unroll
    for (int j = 0; j < SCHUNK; ++j) {
        int i = base + j;
        if (i < NNODES) rowptr[i] = excl + loc[j];
    }
    if (t == 1023) rowptr[NNODES] = sums[1023];
}

__global__ void fill_csr(const int* __restrict__ ei, const int* __restrict__ deg,
                         const int* __restrict__ rowptr, int* __restrict__ cnt,
                         int* __restrict__ esrc, float* __restrict__ ew) {
    int e = blockIdx.x * 256 + threadIdx.x;
    if (e >= NEDGES) return;
    int s = ei[e];
    int d = ei[NEDGES + e];
    float w = rsqrtf((float)(deg[s] + 1)) * rsqrtf((float)(deg[d] + 1));
    int p = rowptr[d] + atomicAdd(&cnt[d], 1);
    esrc[p] = s;
    ew[p] = w;
}

// ---- aggregation: 32-lane half-wave per node, bf16 gathers, f32 accumulate ----
__global__ __launch_bounds__(256) void agg_gather(
        const int* __restrict__ rowptr, const int* __restrict__ esrc,
        const float* __restrict__ ew, const __bf16* __restrict__ hb,
        float* __restrict__ agg) {
    const int tid = blockIdx.x * 256 + threadIdx.x;
    const int n = tid >> 5;
    const int l = tid & 31;
    if (n >= NNODES) return;
    int p  = rowptr[n];
    const int pe = rowptr[n + 1];
    f32x4 acc = {0.0f, 0.0f, 0.0f, 0.0f};
    for (; p + 1 < pe; p += 2) {
        int   s0 = esrc[p],  s1 = esrc[p + 1];
        float w0 = ew[p],    w1 = ew[p + 1];
        bf16x4 v0 = *(const bf16x4*)(hb + (size_t)s0 * DF + l * 4);
        bf16x4 v1 = *(const bf16x4*)(hb + (size_t)s1 * DF + l * 4);
        acc[0] += w0 * (float)v0[0]; acc[1] += w0 * (float)v0[1];
        acc[2] += w0 * (float)v0[2]; acc[3] += w0 * (float)v0[3];
        acc[0] += w1 * (float)v1[0]; acc[1] += w1 * (float)v1[1];
        acc[2] += w1 * (float)v1[2]; acc[3] += w1 * (float)v1[3];
    }
    if (p < pe) {
        int   s0 = esrc[p];
        float w0 = ew[p];
        bf16x4 v0 = *(const bf16x4*)(hb + (size_t)s0 * DF + l * 4);
        acc[0] += w0 * (float)v0[0]; acc[1] += w0 * (float)v0[1];
        acc[2] += w0 * (float)v0[2]; acc[3] += w0 * (float)v0[3];
    }
    *(f32x4*)(agg + (size_t)n * DF + l * 4) = acc;
}

// ---- fused Euler step: out = h + EPS*(kanl(h) + kanc(agg)), concatenated-K GEMM ----
// K = 2560 = 80 chunks of 32. Chunk t<40: branch L (asrc=h, wtl); t>=40: branch C.
// Within a branch (R2 layout): lt -> ic = lt/5 (16-wide i range), p = lt%5 -> planes
// (2p, 2p+1); kk = plane_half*16 + (i - 16*ic). Tile 64 rows x 128 cols; 4 col-split
// waves; A/B LDS double-buffered, 1 barrier per chunk; A elements computed once/block.
__global__ __launch_bounds__(256) void kan_step(
        const float* __restrict__ h, const float* __restrict__ agg,
        const __bf16* __restrict__ wtl, const __bf16* __restrict__ wtc,
        float* __restrict__ out, __bf16* __restrict__ outb) {
    __shared__ __bf16 As[2][64 * 40];    // [buf][row][kk], stride 40 (80 B, 2-way ok)
    __shared__ __bf16 Bs[2][128 * 40];

    const int tid  = threadIdx.x;
    const int lane = tid & 63;
    const int w    = tid >> 6;           // wave -> cols [w*32, w*32+32)
    const int q    = lane >> 4;
    const int l15  = lane & 15;
    const int n0   = blockIdx.x * 64;

    const int arow = tid >> 2;           // A staging: row 0..63
    const int aq   = tid & 3;            // A staging: 4-wide i quarter
    const int gRow = n0 + arow;
    const bool rok = gRow < NNODES;
    const int so   = tid & 127;          // B staging: o
    const int sh   = tid >> 7;           // B staging: plane half

    f32x4 acc[4][2] = {};
    float S[4], Wa[4], Wb[4], Wc[4], Wd[4];
    int IDX[4];

    auto compute_bases = [&](int tn) {   // basis/silu cache for chunk tn's i-range
        const float* asrc = (tn < 40) ? h : agg;
        const int ic = (tn % 40) / 5;
        f32x4 xv = {0.0f, 0.0f, 0.0f, 0.0f};
        if (rok) xv = *(const f32x4*)(asrc + (size_t)gRow * DF + ic * 16 + aq * 4);
#pragma unroll
        for (int j = 0; j < 4; ++j) {
            float x = xv[j];
            float f  = (x + 2.2f) * 2.5f;          // (x - t0)/hstep, t0=-2.2, h=0.4
            float fi = floorf(f);
            IDX[j] = (int)fi;
            float u  = f - fi;
            float u2 = u * u, u3 = u2 * u;
            float om = 1.0f - u;
            Wa[j] = u3 * (1.0f / 6.0f);
            Wb[j] = (((-3.0f * u + 3.0f) * u + 3.0f) * u + 1.0f) * (1.0f / 6.0f);
            Wc[j] = ((3.0f * u - 6.0f) * u2 + 4.0f) * (1.0f / 6.0f);
            Wd[j] = om * om * om * (1.0f / 6.0f);
            S[j]  = x / (1.0f + __expf(-x));       // silu
        }
    };

    auto stage = [&](int t, int buf) {
        const int lt = (t < 40) ? t : t - 40;
        const int ic = lt / 5, p = lt % 5;
        const int c0 = 2 * p, c1 = c0 + 1;
        bf16x4 a0, a1;
#pragma unroll
        for (int j = 0; j < 4; ++j) {
            float v0;
            if (c0 == 0) v0 = S[j];
            else {
                int tt = IDX[j] - (c0 - 1);
                v0 = (tt==0)?Wa[j]:(tt==1)?Wb[j]:(tt==2)?Wc[j]:(tt==3)?Wd[j]:0.0f;
            }
            float v1;
            if (c1 == 9) v1 = 0.0f;
            else {
                int tt = IDX[j] - (c1 - 1);
                v1 = (tt==0)?Wa[j]:(tt==1)?Wb[j]:(tt==2)?Wc[j]:(tt==3)?Wd[j]:0.0f;
            }
            a0[j] = (__bf16)v0;
            a1[j] = (__bf16)v1;
        }
        *(bf16x4*)&As[buf][arow * 40 + aq * 4]      = a0;   // kk = aq*4+j       (c0)
        *(bf16x4*)&As[buf][arow * 40 + 16 + aq * 4] = a1;   // kk = 16+aq*4+j    (c1)
        const __bf16* wt = (t < 40) ? wtl : wtc;
        const uint4* gp = (const uint4*)(wt + (size_t)so * KEXP + (c0 + sh) * DF + ic * 16);
        uint4 g0 = gp[0], g1 = gp[1];
        *(uint4*)&Bs[buf][so * 40 + sh * 16]     = g0;
        *(uint4*)&Bs[buf][so * 40 + sh * 16 + 8] = g1;
    };

    compute_bases(0);
    stage(0, 0);
    __syncthreads();

#pragma unroll 5
    for (int t = 0; t < 80; ++t) {
        const int buf = t & 1;
        if (t + 1 < 80) {
            if (((t + 1) % 5) == 0) compute_bases(t + 1);  // 40%5==0 covers branch switch
            stage(t + 1, buf ^ 1);
        }
        bf16x8 aF[4];
#pragma unroll
        for (int mi = 0; mi < 4; ++mi)
            aF[mi] = *(const bf16x8*)&As[buf][(mi * 16 + l15) * 40 + q * 8];
        bf16x8 bF[2];
#pragma unroll
        for (int nj = 0; nj < 2; ++nj)
            bF[nj] = *(const bf16x8*)&Bs[buf][(w * 32 + nj * 16 + l15) * 40 + q * 8];
#pragma unroll
        for (int mi = 0; mi < 4; ++mi)
#pragma unroll
            for (int nj = 0; nj < 2; ++nj)
                acc[mi][nj] = __builtin_amdgcn_mfma_f32_16x16x32_bf16(
                    aF[mi], bF[nj], acc[mi][nj], 0, 0, 0);
        __syncthreads();
    }

    // epilogue: Euler update; D layout row = q*4+r, col = l15 (m89-verified).
    // In-place (h==out) safe: all expansion reads of h are block-local rows and
    // complete before the final barrier; each (row,col) read+written by one thread.
#pragma unroll
    for (int mi = 0; mi < 4; ++mi) {
#pragma unroll
        for (int nj = 0; nj < 2; ++nj) {
#pragma unroll
            for (int r = 0; r < 4; ++r) {
                int row = n0 + mi * 16 + q * 4 + r;
                int col = w * 32 + nj * 16 + l15;
                if (row < NNODES) {
                    size_t idx = (size_t)row * DF + col;
                    float v = h[idx] + EPS * acc[mi][nj][r];
                    out[idx]  = v;
                    outb[idx] = (__bf16)v;
                }
            }
        }
    }
}

extern "C" void kernel_launch(void* const* d_in, const int* in_sizes, int n_in,
                              void* d_out, int out_size, void* d_ws, size_t ws_size,
                              hipStream_t stream) {
    const float* x   = (const float*)d_in[0];
    const int*   ei  = (const int*)d_in[1];     // edge_index [2,E] int32
    const float* bwl = (const float*)d_in[2];
    const float* swl = (const float*)d_in[3];
    const float* bwc = (const float*)d_in[4];
    const float* swc = (const float*)d_in[5];
    float* out = (float*)d_out;

    char* ws = (char*)d_ws;
    int*    deg    = (int*)  (ws + 0);            //   200,000
    int*    cnt    = (int*)  (ws + 200000);       //   200,000 (adjacent: single memset)
    int*    rowptr = (int*)  (ws + 400000);       //   200,004
    int*    esrc   = (int*)  (ws + 600064);       // 3,200,000
    float*  ew     = (float*)(ws + 3800064);      // 3,200,000
    float*  agg    = (float*)(ws + 7000064);      // 25,600,000
    __bf16* xb     = (__bf16*)(ws + 32600064);    // 12,800,000
    __bf16* wtl    = (__bf16*)(ws + 45400064);    //    327,680
    __bf16* wtc    = (__bf16*)(ws + 45727744);    //    327,680  (total ~46.1 MB)

    build_wt<<<dim3((DF * KEXP) / 256, 2), 256, 0, stream>>>(bwl, swl, bwc, swc, wtl, wtc);
    cast_x<<<3125, 256, 0, stream>>>(x, xb);

    hipMemsetAsync(deg, 0, 400000, stream);       // deg + cnt
    deg_count<<<3125, 256, 0, stream>>>(ei, deg);
    scan_rowptr<<<1, 1024, 0, stream>>>(deg, rowptr);
    fill_csr<<<3125, 256, 0, stream>>>(ei, deg, rowptr, cnt, esrc, ew);

    const int gemm_grid = (NNODES + 63) / 64;     // 782
    const float* h = x;
    for (int step = 0; step < 2; ++step) {        // delta_t = 2
        agg_gather<<<6250, 256, 0, stream>>>(rowptr, esrc, ew, xb, agg);
        kan_step<<<gemm_grid, 256, 0, stream>>>(h, agg, wtl, wtc, out, xb);
        h = out;
    }
}

// Round 6
// 476.692 us; speedup vs baseline: 2.3778x; 1.3364x over previous
//
#include <hip/hip_runtime.h>
#include <hip/hip_bf16.h>

#define NNODES 50000
#define NEDGES 800000
#define DF 128
#define KW 1152                // K per branch: 128 silu + 1024 spline (native order)
#define EPS 0.001f

typedef __bf16 bf16x8 __attribute__((ext_vector_type(8)));
typedef __bf16 bf16x4 __attribute__((ext_vector_type(4)));
typedef float  f32x4  __attribute__((ext_vector_type(4)));

// ---- weight pre-transform: wt[o][k]; k<128 -> bw[o][k]; else sw[o][...] (contiguous) ----
__global__ void build_wt(const float* __restrict__ bwl, const float* __restrict__ swl,
                         const float* __restrict__ bwc, const float* __restrict__ swc,
                         __bf16* __restrict__ wtl, __bf16* __restrict__ wtc) {
    int gid = blockIdx.x * 256 + threadIdx.x;      // 128*1152 = 147456 threads in x
    const float* bw = blockIdx.y ? bwc : bwl;
    const float* sw = blockIdx.y ? swc : swl;
    __bf16*      wt = blockIdx.y ? wtc : wtl;
    int o = gid / KW;
    int k = gid - o * KW;
    float v = (k < 128) ? bw[o * DF + k] : sw[o * 1024 + (k - 128)];
    wt[gid] = (__bf16)v;
}

// ---- bf16 shadow of x (gather traffic halver) ----
__global__ void cast_x(const float* __restrict__ x, __bf16* __restrict__ xb) {
    int i = blockIdx.x * 256 + threadIdx.x;
    f32x4 a = ((const f32x4*)x)[2 * i];
    f32x4 b = ((const f32x4*)x)[2 * i + 1];
    bf16x8 o;
    o[0] = (__bf16)a[0]; o[1] = (__bf16)a[1]; o[2] = (__bf16)a[2]; o[3] = (__bf16)a[3];
    o[4] = (__bf16)b[0]; o[5] = (__bf16)b[1]; o[6] = (__bf16)b[2]; o[7] = (__bf16)b[3];
    ((bf16x8*)xb)[i] = o;
}

// ---------------- CSR build ----------------
__global__ void deg_count(const int* __restrict__ ei, int* __restrict__ deg) {
    int e = blockIdx.x * 256 + threadIdx.x;
    if (e >= NEDGES) return;
    atomicAdd(&deg[ei[NEDGES + e]], 1);
}

#define SCHUNK 49
__global__ __launch_bounds__(1024) void scan_rowptr(const int* __restrict__ deg,
                                                    int* __restrict__ rowptr) {
    __shared__ int sums[1024];
    const int t = threadIdx.x;
    const int base = t * SCHUNK;
    int loc[SCHUNK];
    int s = 0;
#pragma unroll
    for (int j = 0; j < SCHUNK; ++j) {
        int i = base + j;
        int v = (i < NNODES) ? deg[i] : 0;
        loc[j] = s;
        s += v;
    }
    sums[t] = s;
    __syncthreads();
    for (int off = 1; off < 1024; off <<= 1) {
        int v = (t >= off) ? sums[t - off] : 0;
        __syncthreads();
        sums[t] += v;
        __syncthreads();
    }
    int excl = sums[t] - s;
#pragma unroll
    for (int j = 0; j < SCHUNK; ++j) {
        int i = base + j;
        if (i < NNODES) rowptr[i] = excl + loc[j];
    }
    if (t == 1023) rowptr[NNODES] = sums[1023];
}

__global__ void fill_csr(const int* __restrict__ ei, const int* __restrict__ deg,
                         const int* __restrict__ rowptr, int* __restrict__ cnt,
                         int* __restrict__ esrc, float* __restrict__ ew) {
    int e = blockIdx.x * 256 + threadIdx.x;
    if (e >= NEDGES) return;
    int s = ei[e];
    int d = ei[NEDGES + e];
    float w = rsqrtf((float)(deg[s] + 1)) * rsqrtf((float)(deg[d] + 1));
    int p = rowptr[d] + atomicAdd(&cnt[d], 1);
    esrc[p] = s;
    ew[p] = w;
}

// ---- aggregation: 32-lane half-wave per node, bf16 gathers, unroll-4 ----
__global__ __launch_bounds__(256) void agg_gather(
        const int* __restrict__ rowptr, const int* __restrict__ esrc,
        const float* __restrict__ ew, const __bf16* __restrict__ hb,
        float* __restrict__ agg) {
    const int tid = blockIdx.x * 256 + threadIdx.x;
    const int n = tid >> 5;
    const int l = tid & 31;
    if (n >= NNODES) return;
    int p  = rowptr[n];
    const int pe = rowptr[n + 1];
    f32x4 acc = {0.0f, 0.0f, 0.0f, 0.0f};
    for (; p + 3 < pe; p += 4) {
        int   s0 = esrc[p],  s1 = esrc[p + 1], s2 = esrc[p + 2], s3 = esrc[p + 3];
        float w0 = ew[p],    w1 = ew[p + 1],   w2 = ew[p + 2],   w3 = ew[p + 3];
        bf16x4 v0 = *(const bf16x4*)(hb + (size_t)s0 * DF + l * 4);
        bf16x4 v1 = *(const bf16x4*)(hb + (size_t)s1 * DF + l * 4);
        bf16x4 v2 = *(const bf16x4*)(hb + (size_t)s2 * DF + l * 4);
        bf16x4 v3 = *(const bf16x4*)(hb + (size_t)s3 * DF + l * 4);
#pragma unroll
        for (int j = 0; j < 4; ++j)
            acc[j] += w0 * (float)v0[j] + w1 * (float)v1[j]
                    + w2 * (float)v2[j] + w3 * (float)v3[j];
    }
    for (; p < pe; ++p) {
        int   s0 = esrc[p];
        float w0 = ew[p];
        bf16x4 v0 = *(const bf16x4*)(hb + (size_t)s0 * DF + l * 4);
#pragma unroll
        for (int j = 0; j < 4; ++j) acc[j] += w0 * (float)v0[j];
    }
    *(f32x4*)(agg + (size_t)n * DF + l * 4) = acc;
}

// ---- fused Euler step: out = h + EPS*(kanl(h) + kanc(agg)) -------------------
// Concatenated K = 2*1152 -> 72 chunks of 32. t<36: branch L (h,wtl); else C (agg,wtc).
// k-order per branch: [0,128) silu(i); [128,1152) spline k=128+i*8+b (native sw order).
// Spline A staging: zero 16B slot + scatter 4 basis weights by cell idx (no selects).
// Tile 64 rows x 128 cols, 4 col-split waves, A/B LDS double-buffered, 1 barrier/chunk.
__global__ __launch_bounds__(256) void kan_step(
        const float* __restrict__ h, const float* __restrict__ agg,
        const __bf16* __restrict__ wtl, const __bf16* __restrict__ wtc,
        float* __restrict__ out, __bf16* __restrict__ outb) {
    __shared__ __bf16 As[2][64 * 40];    // [buf][row][kk], stride 40 (80 B, 2-way ok)
    __shared__ __bf16 Bs[2][128 * 40];   // kk 32..39 = pad (scatter dump / conflict pad)

    const int tid  = threadIdx.x;
    const int lane = tid & 63;
    const int w    = tid >> 6;           // wave -> cols [w*32, w*32+32)
    const int q    = lane >> 4;
    const int l15  = lane & 15;
    const int n0   = blockIdx.x * 64;

    const int arow = tid >> 2;           // A staging: row 0..63
    const int aq   = tid & 3;            // A staging: i-quarter / 8-slot group
    const int gRow = n0 + arow;
    const bool rok = gRow < NNODES;
    const size_t arow_off = (size_t)gRow * DF;
    const int abase = arow * 40 + aq * 8;
    const int adump = arow * 40 + 36;    // in-row pad, never read
    const int so = tid & 127;            // B staging: o
    const int sh = tid >> 7;             // B staging: 16-kk half
    const int bbase = so * 40 + sh * 16;
    const int wrow  = so * KW + sh * 16;

    f32x4 acc[4][2] = {};

    auto stage = [&](int tn, int buf) {
        const int br = tn >= 36;
        const int ck = br ? tn - 36 : tn;
        const float*  asrc = br ? agg : h;
        const __bf16* wtp  = br ? wtc : wtl;
        __bf16* Ab = As[buf];
        __bf16* Bb = Bs[buf];
        const uint4* gp = (const uint4*)(wtp + wrow + ck * 32);
        uint4 g0 = gp[0], g1 = gp[1];
        if (ck < 4) {
            // silu chunk: kk = iq*8 + j over i = ck*32 + kk
            const int i0 = ck * 32 + aq * 8;
            f32x4 xa = {0, 0, 0, 0}, xb2 = {0, 0, 0, 0};
            if (rok) {
                xa  = *(const f32x4*)(asrc + arow_off + i0);
                xb2 = *(const f32x4*)(asrc + arow_off + i0 + 4);
            }
            bf16x8 o;
#pragma unroll
            for (int j = 0; j < 4; ++j) { float x = xa[j];  o[j]     = (__bf16)(x / (1.0f + __expf(-x))); }
#pragma unroll
            for (int j = 0; j < 4; ++j) { float x = xb2[j]; o[4 + j] = (__bf16)(x / (1.0f + __expf(-x))); }
            *(bf16x8*)&Ab[abase] = o;
        } else {
            // spline chunk: one feature i = (ck-4)*4 + aq; kk = aq*8 + b
            const int ii = (ck - 4) * 4 + aq;
            float x = rok ? asrc[arow_off + ii] : 0.0f;
            float f  = (x + 2.2f) * 2.5f;          // (x - t0)/hstep, t0=-2.2, h=0.4
            float fi = floorf(f);
            int idx = (int)fi;
            float u  = f - fi;
            float u2 = u * u, u3 = u2 * u;
            float om = 1.0f - u;
            float Wa = u3 * (1.0f / 6.0f);
            float Wb = (((-3.0f * u + 3.0f) * u + 3.0f) * u + 1.0f) * (1.0f / 6.0f);
            float Wc = ((3.0f * u - 6.0f) * u2 + 4.0f) * (1.0f / 6.0f);
            float Wd = om * om * om * (1.0f / 6.0f);
            bf16x8 z = {};
            *(bf16x8*)&Ab[abase] = z;              // same-thread in-order LDS ops
            const int b0 = idx - 3;                // nonzero bases: b0..b0+3 = Wd,Wc,Wb,Wa
            Ab[((unsigned)(b0    ) < 8u) ? abase + b0     : adump] = (__bf16)Wd;
            Ab[((unsigned)(b0 + 1) < 8u) ? abase + b0 + 1 : adump] = (__bf16)Wc;
            Ab[((unsigned)(b0 + 2) < 8u) ? abase + b0 + 2 : adump] = (__bf16)Wb;
            Ab[((unsigned)(b0 + 3) < 8u) ? abase + b0 + 3 : adump] = (__bf16)Wa;
        }
        *(uint4*)&Bb[bbase]     = g0;
        *(uint4*)&Bb[bbase + 8] = g1;
    };

    stage(0, 0);
    __syncthreads();

#pragma unroll 4
    for (int t = 0; t < 72; ++t) {
        const int buf = t & 1;
        if (t + 1 < 72) stage(t + 1, buf ^ 1);
        const __bf16* Ab = As[buf];
        const __bf16* Bb = Bs[buf];
        bf16x8 aF[4], bF[2];
#pragma unroll
        for (int mi = 0; mi < 4; ++mi)
            aF[mi] = *(const bf16x8*)&Ab[(mi * 16 + l15) * 40 + q * 8];
#pragma unroll
        for (int nj = 0; nj < 2; ++nj)
            bF[nj] = *(const bf16x8*)&Bb[(w * 32 + nj * 16 + l15) * 40 + q * 8];
#pragma unroll
        for (int mi = 0; mi < 4; ++mi)
#pragma unroll
            for (int nj = 0; nj < 2; ++nj)
                acc[mi][nj] = __builtin_amdgcn_mfma_f32_16x16x32_bf16(
                    aF[mi], bF[nj], acc[mi][nj], 0, 0, 0);
        __syncthreads();
    }

    // epilogue: Euler update; D layout row = q*4+r, col = l15 (m89-verified).
    // In-place (h==out) safe: expansion reads of h are block-local rows, done above.
#pragma unroll
    for (int mi = 0; mi < 4; ++mi) {
#pragma unroll
        for (int nj = 0; nj < 2; ++nj) {
#pragma unroll
            for (int r = 0; r < 4; ++r) {
                int row = n0 + mi * 16 + q * 4 + r;
                int col = w * 32 + nj * 16 + l15;
                if (row < NNODES) {
                    size_t idx = (size_t)row * DF + col;
                    float v = h[idx] + EPS * acc[mi][nj][r];
                    out[idx]  = v;
                    outb[idx] = (__bf16)v;
                }
            }
        }
    }
}

extern "C" void kernel_launch(void* const* d_in, const int* in_sizes, int n_in,
                              void* d_out, int out_size, void* d_ws, size_t ws_size,
                              hipStream_t stream) {
    const float* x   = (const float*)d_in[0];
    const int*   ei  = (const int*)d_in[1];     // edge_index [2,E] int32
    const float* bwl = (const float*)d_in[2];
    const float* swl = (const float*)d_in[3];
    const float* bwc = (const float*)d_in[4];
    const float* swc = (const float*)d_in[5];
    float* out = (float*)d_out;

    char* ws = (char*)d_ws;
    int*    deg    = (int*)  (ws + 0);            //   200,000
    int*    cnt    = (int*)  (ws + 200000);       //   200,000 (adjacent: single memset)
    int*    rowptr = (int*)  (ws + 400000);       //   200,004
    int*    esrc   = (int*)  (ws + 600064);       // 3,200,000
    float*  ew     = (float*)(ws + 3800064);      // 3,200,000
    float*  agg    = (float*)(ws + 7000064);      // 25,600,000
    __bf16* xb     = (__bf16*)(ws + 32600064);    // 12,800,000
    __bf16* wtl    = (__bf16*)(ws + 45400064);    //   294,912
    __bf16* wtc    = (__bf16*)(ws + 45694976);    //   294,912  (total ~46.0 MB)

    build_wt<<<dim3((DF * KW) / 256, 2), 256, 0, stream>>>(bwl, swl, bwc, swc, wtl, wtc);
    cast_x<<<3125, 256, 0, stream>>>(x, xb);

    hipMemsetAsync(deg, 0, 400000, stream);       // deg + cnt
    deg_count<<<3125, 256, 0, stream>>>(ei, deg);
    scan_rowptr<<<1, 1024, 0, stream>>>(deg, rowptr);
    fill_csr<<<3125, 256, 0, stream>>>(ei, deg, rowptr, cnt, esrc, ew);

    const int gemm_grid = (NNODES + 63) / 64;     // 782
    const float* h = x;
    for (int step = 0; step < 2; ++step) {        // delta_t = 2
        agg_gather<<<6250, 256, 0, stream>>>(rowptr, esrc, ew, xb, agg);
        kan_step<<<gemm_grid, 256, 0, stream>>>(h, agg, wtl, wtc, out, xb);
        h = out;
    }
}